// Round 9
// baseline (76.755 us; speedup 1.0000x reference)
//
#include <hip/hip_runtime.h>
#include <hip/hip_bf16.h>

typedef __bf16 bf16x8 __attribute__((ext_vector_type(8)));
typedef float  f32x4  __attribute__((ext_vector_type(4)));
typedef float  f32x16 __attribute__((ext_vector_type(16)));

#define BN_EPS 1e-5f
#define NROWS 131072
#define TPB 512               // 8 waves; wave owns 32 rows x all 256 cols
#define BM 256                // rows per block
#define NBLOCKS (NROWS / BM)  // 512

#define WAITVM(N) asm volatile("s_waitcnt vmcnt(" #N ")" ::: "memory")

__device__ __forceinline__ void gll16(const void* g, void* l) {
    __builtin_amdgcn_global_load_lds(
        (const __attribute__((address_space(1))) void*)g,
        (__attribute__((address_space(3))) void*)l, 16, 0, 0);
}

// ws layout (bytes):
//   [0, 262144)        W0 packed bf16 for 32x32x16 B-frags:
//                      flat = ((s*8 + t)*64 + lane)*8 + j
//                      n = t*32 + (lane&31); k = s*16 + (lane>>5)*8 + j ; s in [0,32)
//   [262144, 264192)   a_fused f32[512]
//   [264192, 266240)   c_fused f32[512]
//   [266240, 267264)   A_fc f32[256]
//   [267264, 268288)   C_fc f32[256] (b0 folded in)

__global__ __launch_bounds__(256) void setup_kernel(
    const float* __restrict__ W0,
    const float* __restrict__ imu_gamma, const float* __restrict__ imu_beta,
    const float* __restrict__ imu_mean,  const float* __restrict__ imu_var,
    const float* __restrict__ frame_gamma, const float* __restrict__ frame_beta,
    const float* __restrict__ frame_mean,  const float* __restrict__ frame_var,
    const float* __restrict__ b0,
    const float* __restrict__ fc_gamma, const float* __restrict__ fc_beta,
    const float* __restrict__ fc_mean,  const float* __restrict__ fc_var,
    void* __restrict__ ws)
{
    __bf16* w0p    = (__bf16*)ws;
    float* a_fused = (float*)((char*)ws + 262144);
    float* c_fused = a_fused + 512;
    float* A_fc    = c_fused + 512;
    float* C_fc    = A_fc + 256;

    const int b = blockIdx.x;
    if (b < 512) {
        const int flat = b * 256 + threadIdx.x;
        const int j    = flat & 7;
        const int lane = (flat >> 3) & 63;
        const int t    = (flat >> 9) & 7;
        const int s    = flat >> 12;                  // 0..31
        const int n    = t * 32 + (lane & 31);
        const int k    = s * 16 + ((lane >> 5) << 3) + j;
        w0p[flat] = (__bf16)W0[n * 512 + k];
    } else {
        const int t = threadIdx.x;
        const float af = frame_gamma[t] / sqrtf(frame_var[t] + BN_EPS);
        a_fused[t]       = af;
        c_fused[t]       = frame_beta[t] - frame_mean[t] * af;
        const float ai = imu_gamma[t] / sqrtf(imu_var[t] + BN_EPS);
        a_fused[256 + t] = ai;
        c_fused[256 + t] = imu_beta[t] - imu_mean[t] * ai;
        const float A = fc_gamma[t] / sqrtf(fc_var[t] + BN_EPS);
        A_fc[t] = A;
        C_fc[t] = fc_beta[t] - fc_mean[t] * A + A * b0[t];
    }
}

__global__ __launch_bounds__(TPB, 1) void fusion_main(
    const float* __restrict__ frame, const float* __restrict__ imu,
    const float* __restrict__ W1,    const float* __restrict__ b1,
    const void* __restrict__ ws_c,   float* __restrict__ out)
{
    const __bf16* w0p  = (const __bf16*)ws_c;
    const float*  a_g  = (const float*)((const char*)ws_c + 262144);
    const float*  c_g  = a_g + 512;
    const float*  A_fc = c_g + 512;
    const float*  C_fc = A_fc + 256;

    __shared__ __align__(16) __bf16 wpan[3][8192];   // 3 x 16 KB W0 panels (distance-2 prefetch)
    __shared__ __align__(16) float  ring[8][5][512]; // per-wave 4-slot ring + dummy slot
    __shared__ float asx[512], csx[512];

    const int tid  = threadIdx.x;
    const int wave = tid >> 6;
    const int lane = tid & 63;
    const int row  = lane & 31;   // A-frag row / C col index
    const int hi   = lane >> 5;
    const size_t rowW = (size_t)blockIdx.x * BM + wave * 32;

    // chunk c = one k-step (k=16): 32 rows x 16 f32 = 2 KB = 2 gll.
    // physical granule p at slot-row r holds logical granule p ^ ((r>>1)&3)
    // (involution; spreads a 16-lane read phase 2x over every 4-bank group).
    const int fr = lane >> 2;                         // 0..15
    const int fg = (lane & 3) ^ ((lane >> 3) & 3);    // logical granule this lane fetches

    auto issueF = [&](int c) {
        const int cc   = (c < 31) ? c : 31;
        const int slot = (c < 32) ? (c & 3) : 4;
        const float* srcp = (cc < 16) ? frame : imu;
        const int kb = (cc & 15) * 16;
        float* dstb = &ring[wave][slot][0];
        gll16(srcp + (rowW + fr) * 256 + kb + fg * 4, dstb);
        gll16(srcp + (rowW + 16 + fr) * 256 + kb + fg * 4, dstb + 256);
    };
    auto issueW = [&](int e) {
        const int ee = (e < 15) ? e : 15;
        const char* src = (const char*)w0p + ee * 16384 + wave * 2048 + lane * 16;
        char* dst = (char*)&wpan[e % 3][0] + wave * 2048;
        gll16(src, dst);
        gll16(src + 1024, dst + 1024);
    };

    // ---- prologue ----
    asx[tid] = a_g[tid];
    csx[tid] = c_g[tid];
    asm volatile("s_waitcnt vmcnt(0)" ::: "memory");   // clean vm queue for counted waits
    issueW(0);
    issueF(0);
    issueW(1);
    issueF(1);
    issueF(2);
    WAITVM(8);                    // retire W(0); queue = [F0,W1,F1,F2]
    asm volatile("s_waitcnt lgkmcnt(0)" ::: "memory");
    __builtin_amdgcn_s_barrier();

    f32x16 acc[8];
    #pragma unroll
    for (int t = 0; t < 8; ++t)
        #pragma unroll
        for (int r = 0; r < 16; ++r) acc[t][r] = 0.f;

    auto stepc = [&](int s, int pan3, int s2) {
        const float* sb = &ring[wave][s & 3][0];
        const int sw = (row >> 1) & 3;
        const int g0 = hi * 2;
        const f32x4 x0 = *(const f32x4*)(sb + row * 16 + (((g0 + 0) ^ sw) << 2));
        const f32x4 x1 = *(const f32x4*)(sb + row * 16 + (((g0 + 1) ^ sw) << 2));
        const int kf = s * 16 + hi * 8;
        const f32x4 a0 = *(const f32x4*)(asx + kf);
        const f32x4 a1 = *(const f32x4*)(asx + kf + 4);
        const f32x4 c0 = *(const f32x4*)(csx + kf);
        const f32x4 c1 = *(const f32x4*)(csx + kf + 4);
        bf16x8 af;
        af[0] = (__bf16)fmaxf(fmaf(a0[0], x0[0], c0[0]), 0.f);
        af[1] = (__bf16)fmaxf(fmaf(a0[1], x0[1], c0[1]), 0.f);
        af[2] = (__bf16)fmaxf(fmaf(a0[2], x0[2], c0[2]), 0.f);
        af[3] = (__bf16)fmaxf(fmaf(a0[3], x0[3], c0[3]), 0.f);
        af[4] = (__bf16)fmaxf(fmaf(a1[0], x1[0], c1[0]), 0.f);
        af[5] = (__bf16)fmaxf(fmaf(a1[1], x1[1], c1[1]), 0.f);
        af[6] = (__bf16)fmaxf(fmaf(a1[2], x1[2], c1[2]), 0.f);
        af[7] = (__bf16)fmaxf(fmaf(a1[3], x1[3], c1[3]), 0.f);
        const __bf16* pan = &wpan[pan3][0];
        #pragma unroll
        for (int t = 0; t < 8; ++t) {
            const bf16x8 bfr = *(const bf16x8*)(pan + ((s2 * 8 + t) * 64 + lane) * 8);
            acc[t] = __builtin_amdgcn_mfma_f32_32x32x16_bf16(af, bfr, acc[t], 0, 0, 0);
        }
    };

    // steady state (queue oldest->newest at phase p entry): [F(2p),W(p+1),F(2p+1),F(2p+2)]
    //   +W(p+2) +F(2p+3) -> WAITVM(10) retires F(2p)   [issued 2 phases ago]
    //   stepc(2p) -> +F(2p+4) -> WAITVM(8) retires W(p+1),F(2p+1)  [>=1 phase old]
    //   stepc(2p+1) -> barrier   (W(p+1) for next phase already retired)
    #pragma unroll
    for (int p = 0; p < 16; ++p) {
        const int c = 2 * p;
        issueW(p + 2);
        issueF(c + 3);
        WAITVM(10);
        stepc(c, p % 3, 0);
        issueF(c + 4);
        WAITVM(8);
        stepc(c + 1, p % 3, 1);
        __builtin_amdgcn_s_barrier();
    }
    WAITVM(0);   // drain dummy glls before epilogue

    // ---- epilogue: fc BN+ReLU + fc1 + ReLU + clamp ----
    // C/D (32x32): col = t*32 + (lane&31), row-in-tile = (r&3) + 8*(r>>2) + 4*hi
    const float b1_0 = b1[0], b1_1 = b1[1];
    float p0[16], p1[16];
    #pragma unroll
    for (int r = 0; r < 16; ++r) { p0[r] = 0.f; p1[r] = 0.f; }

    #pragma unroll
    for (int t = 0; t < 8; ++t) {
        const int n = t * 32 + row;
        const float A = A_fc[n], C = C_fc[n];
        const float w0n = W1[n], w1n = W1[256 + n];
        #pragma unroll
        for (int r = 0; r < 16; ++r) {
            const float h = fmaxf(fmaf(A, acc[t][r], C), 0.f);
            p0[r] = fmaf(h, w0n, p0[r]);
            p1[r] = fmaf(h, w1n, p1[r]);
        }
    }
    #pragma unroll
    for (int off = 1; off < 32; off <<= 1) {
        #pragma unroll
        for (int r = 0; r < 16; ++r) {
            p0[r] += __shfl_xor(p0[r], off, 64);
            p1[r] += __shfl_xor(p1[r], off, 64);
        }
    }
    if (row == 0) {   // lanes 0 and 32 each write 16 rows
        #pragma unroll
        for (int r = 0; r < 16; ++r) {
            const int rbase = (r & 3) + 8 * (r >> 2) + 4 * hi;
            const float v0 = fminf(fmaxf(p0[r] + b1_0, 0.f), 512.f);
            const float v1 = fminf(fmaxf(p1[r] + b1_1, 0.f), 384.f);
            *(float2*)(out + (rowW + rbase) * 2) = make_float2(v0, v1);
        }
    }
}

extern "C" void kernel_launch(void* const* d_in, const int* in_sizes, int n_in,
                              void* d_out, int out_size, void* d_ws, size_t ws_size,
                              hipStream_t stream) {
    const float* frame_feat  = (const float*)d_in[0];
    const float* imu_feat    = (const float*)d_in[1];
    const float* imu_gamma   = (const float*)d_in[2];
    const float* imu_beta    = (const float*)d_in[3];
    const float* imu_mean    = (const float*)d_in[4];
    const float* imu_var     = (const float*)d_in[5];
    const float* frame_gamma = (const float*)d_in[6];
    const float* frame_beta  = (const float*)d_in[7];
    const float* frame_mean  = (const float*)d_in[8];
    const float* frame_var   = (const float*)d_in[9];
    const float* W0          = (const float*)d_in[10];
    const float* b0          = (const float*)d_in[11];
    const float* fc_gamma    = (const float*)d_in[12];
    const float* fc_beta     = (const float*)d_in[13];
    const float* fc_mean     = (const float*)d_in[14];
    const float* fc_var      = (const float*)d_in[15];
    const float* W1          = (const float*)d_in[16];
    const float* b1          = (const float*)d_in[17];

    setup_kernel<<<513, 256, 0, stream>>>(
        W0, imu_gamma, imu_beta, imu_mean, imu_var,
        frame_gamma, frame_beta, frame_mean, frame_var,
        b0, fc_gamma, fc_beta, fc_mean, fc_var, d_ws);

    fusion_main<<<NBLOCKS, TPB, 0, stream>>>(
        frame_feat, imu_feat, W1, b1, d_ws, (float*)d_out);
}

// Round 10
// 73.691 us; speedup vs baseline: 1.0416x; 1.0416x over previous
//
#include <hip/hip_runtime.h>
#include <hip/hip_bf16.h>

typedef __bf16 bf16x8 __attribute__((ext_vector_type(8)));
typedef float  f32x4  __attribute__((ext_vector_type(4)));
typedef float  f32x16 __attribute__((ext_vector_type(16)));

#define BN_EPS 1e-5f
#define NROWS 131072
#define TPB 256               // 4 waves; wave owns 32 rows x all 256 cols
#define BM 128                // rows per block
#define NBLOCKS (NROWS / BM)  // 1024

#define WAITVM(N) asm volatile("s_waitcnt vmcnt(" #N ")" ::: "memory")

__device__ __forceinline__ void gll16(const void* g, void* l) {
    __builtin_amdgcn_global_load_lds(
        (const __attribute__((address_space(1))) void*)g,
        (__attribute__((address_space(3))) void*)l, 16, 0, 0);
}

// ws layout (bytes):
//   [0, 262144)        W0 packed bf16 for 32x32x16 B-frags:
//                      flat = ((s*8 + t)*64 + lane)*8 + j
//                      n = t*32 + (lane&31); k = s*16 + (lane>>5)*8 + j ; s in [0,32)
//   [262144, 264192)   a_fused f32[512]
//   [264192, 266240)   c_fused f32[512]
//   [266240, 267264)   A_fc f32[256]
//   [267264, 268288)   C_fc f32[256] (b0 folded in)

__global__ __launch_bounds__(256) void setup_kernel(
    const float* __restrict__ W0,
    const float* __restrict__ imu_gamma, const float* __restrict__ imu_beta,
    const float* __restrict__ imu_mean,  const float* __restrict__ imu_var,
    const float* __restrict__ frame_gamma, const float* __restrict__ frame_beta,
    const float* __restrict__ frame_mean,  const float* __restrict__ frame_var,
    const float* __restrict__ b0,
    const float* __restrict__ fc_gamma, const float* __restrict__ fc_beta,
    const float* __restrict__ fc_mean,  const float* __restrict__ fc_var,
    void* __restrict__ ws)
{
    __bf16* w0p    = (__bf16*)ws;
    float* a_fused = (float*)((char*)ws + 262144);
    float* c_fused = a_fused + 512;
    float* A_fc    = c_fused + 512;
    float* C_fc    = A_fc + 256;

    const int b = blockIdx.x;
    if (b < 512) {
        const int flat = b * 256 + threadIdx.x;
        const int j    = flat & 7;
        const int lane = (flat >> 3) & 63;
        const int t    = (flat >> 9) & 7;
        const int s    = flat >> 12;                  // 0..31
        const int n    = t * 32 + (lane & 31);
        const int k    = s * 16 + ((lane >> 5) << 3) + j;
        w0p[flat] = (__bf16)W0[n * 512 + k];
    } else {
        const int t = threadIdx.x;
        const float af = frame_gamma[t] / sqrtf(frame_var[t] + BN_EPS);
        a_fused[t]       = af;
        c_fused[t]       = frame_beta[t] - frame_mean[t] * af;
        const float ai = imu_gamma[t] / sqrtf(imu_var[t] + BN_EPS);
        a_fused[256 + t] = ai;
        c_fused[256 + t] = imu_beta[t] - imu_mean[t] * ai;
        const float A = fc_gamma[t] / sqrtf(fc_var[t] + BN_EPS);
        A_fc[t] = A;
        C_fc[t] = fc_beta[t] - fc_mean[t] * A + A * b0[t];
    }
}

__global__ __launch_bounds__(TPB, 1) void fusion_main(
    const float* __restrict__ frame, const float* __restrict__ imu,
    const float* __restrict__ W1,    const float* __restrict__ b1,
    const void* __restrict__ ws_c,   float* __restrict__ out)
{
    const __bf16* w0p  = (const __bf16*)ws_c;
    const float*  a_g  = (const float*)((const char*)ws_c + 262144);
    const float*  c_g  = a_g + 512;
    const float*  A_fc = c_g + 512;
    const float*  C_fc = A_fc + 256;

    // 68 KB total -> 2 blocks/CU (two independent barrier domains)
    __shared__ __align__(16) __bf16 wpan[4][4096];   // 4 x 8 KB single-k-step W0 panels
    __shared__ __align__(16) float  ring[4][4][512]; // per-wave 4-slot feature ring (2 KB slots)
    __shared__ float asx[512], csx[512];

    const int tid  = threadIdx.x;
    const int wave = tid >> 6;
    const int lane = tid & 63;
    const int row  = lane & 31;   // A-frag row / C col index
    const int hi   = lane >> 5;
    const size_t rowW = (size_t)blockIdx.x * BM + wave * 32;

    // chunk c = one k-step (k=16): 32 rows x 16 f32 = 2 KB = 2 gll.
    // physical granule p at slot-row r holds logical granule p ^ ((r>>1)&3).
    const int fr = lane >> 2;                         // 0..15
    const int fg = (lane & 3) ^ ((lane >> 3) & 3);    // logical granule this lane fetches

    auto issueF = [&](int c) {
        const int cc = (c < 31) ? c : 31;             // tail: re-load last chunk
        const int slot = c & 3;                       // tail slots are provably dead
        const float* srcp = (cc < 16) ? frame : imu;
        const int kb = (cc & 15) * 16;
        float* dstb = &ring[wave][slot][0];
        gll16(srcp + (rowW + fr) * 256 + kb + fg * 4, dstb);
        gll16(srcp + (rowW + 16 + fr) * 256 + kb + fg * 4, dstb + 256);
    };
    auto issueW = [&](int e) {
        const int ee = (e < 31) ? e : 31;             // tail: re-load last panel
        const char* src = (const char*)w0p + ee * 8192 + wave * 1024 + lane * 16;
        char* dst = (char*)&wpan[e & 3][0] + wave * 1024;   // tail panels are dead
        gll16(src, dst);
        gll16(src + 4096, dst + 4096);
    };

    // ---- prologue ----
    asx[tid] = a_g[tid];
    asx[tid + 256] = a_g[tid + 256];
    csx[tid] = c_g[tid];
    csx[tid + 256] = c_g[tid + 256];
    asm volatile("s_waitcnt vmcnt(0)" ::: "memory");   // clean vm queue for counted waits
    issueW(0);
    issueW(1);
    issueF(0);
    issueF(1);
    issueF(2);
    WAITVM(4);                    // retire W0,W1,F0; queue = [F1,F2]
    asm volatile("s_waitcnt lgkmcnt(0)" ::: "memory");
    __builtin_amdgcn_s_barrier();

    f32x16 acc[8];
    #pragma unroll
    for (int t = 0; t < 8; ++t)
        #pragma unroll
        for (int r = 0; r < 16; ++r) acc[t][r] = 0.f;

    auto stepc = [&](int s) {
        const float* sb = &ring[wave][s & 3][0];
        const int sw = (row >> 1) & 3;
        const int g0 = hi * 2;
        const f32x4 x0 = *(const f32x4*)(sb + row * 16 + (((g0 + 0) ^ sw) << 2));
        const f32x4 x1 = *(const f32x4*)(sb + row * 16 + (((g0 + 1) ^ sw) << 2));
        const int kf = s * 16 + hi * 8;
        const f32x4 a0 = *(const f32x4*)(asx + kf);
        const f32x4 a1 = *(const f32x4*)(asx + kf + 4);
        const f32x4 c0 = *(const f32x4*)(csx + kf);
        const f32x4 c1 = *(const f32x4*)(csx + kf + 4);
        bf16x8 af;
        af[0] = (__bf16)fmaxf(fmaf(a0[0], x0[0], c0[0]), 0.f);
        af[1] = (__bf16)fmaxf(fmaf(a0[1], x0[1], c0[1]), 0.f);
        af[2] = (__bf16)fmaxf(fmaf(a0[2], x0[2], c0[2]), 0.f);
        af[3] = (__bf16)fmaxf(fmaf(a0[3], x0[3], c0[3]), 0.f);
        af[4] = (__bf16)fmaxf(fmaf(a1[0], x1[0], c1[0]), 0.f);
        af[5] = (__bf16)fmaxf(fmaf(a1[1], x1[1], c1[1]), 0.f);
        af[6] = (__bf16)fmaxf(fmaf(a1[2], x1[2], c1[2]), 0.f);
        af[7] = (__bf16)fmaxf(fmaf(a1[3], x1[3], c1[3]), 0.f);
        const __bf16* pan = &wpan[s & 3][0];
        #pragma unroll
        for (int t = 0; t < 8; ++t) {
            const bf16x8 bfr = *(const bf16x8*)(pan + (t * 64 + lane) * 8);
            acc[t] = __builtin_amdgcn_mfma_f32_32x32x16_bf16(af, bfr, acc[t], 0, 0, 0);
        }
    };

    // steady phase s: entry queue [F(s+1), W(s+1), F(s+2)]
    //   +W(s+2) +F(s+3) -> stepc(s) -> WAITVM(6) retires F(s+1) [2 phases old],
    //   W(s+1) [1 phase old] -> barrier.
    #pragma unroll
    for (int s = 0; s < 32; ++s) {
        issueW(s + 2);
        issueF(s + 3);
        stepc(s);
        WAITVM(6);
        __builtin_amdgcn_s_barrier();
    }
    WAITVM(0);   // drain dangling tail glls before wave exit

    // ---- epilogue: fc BN+ReLU + fc1 + ReLU + clamp ----
    // C/D (32x32): col = t*32 + (lane&31), row-in-tile = (r&3) + 8*(r>>2) + 4*hi
    const float b1_0 = b1[0], b1_1 = b1[1];
    float p0[16], p1[16];
    #pragma unroll
    for (int r = 0; r < 16; ++r) { p0[r] = 0.f; p1[r] = 0.f; }

    #pragma unroll
    for (int t = 0; t < 8; ++t) {
        const int n = t * 32 + row;
        const float A = A_fc[n], C = C_fc[n];
        const float w0n = W1[n], w1n = W1[256 + n];
        #pragma unroll
        for (int r = 0; r < 16; ++r) {
            const float h = fmaxf(fmaf(A, acc[t][r], C), 0.f);
            p0[r] = fmaf(h, w0n, p0[r]);
            p1[r] = fmaf(h, w1n, p1[r]);
        }
    }
    #pragma unroll
    for (int off = 1; off < 32; off <<= 1) {
        #pragma unroll
        for (int r = 0; r < 16; ++r) {
            p0[r] += __shfl_xor(p0[r], off, 64);
            p1[r] += __shfl_xor(p1[r], off, 64);
        }
    }
    if (row == 0) {   // lanes 0 and 32 each write 16 rows
        #pragma unroll
        for (int r = 0; r < 16; ++r) {
            const int rbase = (r & 3) + 8 * (r >> 2) + 4 * hi;
            const float v0 = fminf(fmaxf(p0[r] + b1_0, 0.f), 512.f);
            const float v1 = fminf(fmaxf(p1[r] + b1_1, 0.f), 384.f);
            *(float2*)(out + (rowW + rbase) * 2) = make_float2(v0, v1);
        }
    }
}

extern "C" void kernel_launch(void* const* d_in, const int* in_sizes, int n_in,
                              void* d_out, int out_size, void* d_ws, size_t ws_size,
                              hipStream_t stream) {
    const float* frame_feat  = (const float*)d_in[0];
    const float* imu_feat    = (const float*)d_in[1];
    const float* imu_gamma   = (const float*)d_in[2];
    const float* imu_beta    = (const float*)d_in[3];
    const float* imu_mean    = (const float*)d_in[4];
    const float* imu_var     = (const float*)d_in[5];
    const float* frame_gamma = (const float*)d_in[6];
    const float* frame_beta  = (const float*)d_in[7];
    const float* frame_mean  = (const float*)d_in[8];
    const float* frame_var   = (const float*)d_in[9];
    const float* W0          = (const float*)d_in[10];
    const float* b0          = (const float*)d_in[11];
    const float* fc_gamma    = (const float*)d_in[12];
    const float* fc_beta     = (const float*)d_in[13];
    const float* fc_mean     = (const float*)d_in[14];
    const float* fc_var      = (const float*)d_in[15];
    const float* W1          = (const float*)d_in[16];
    const float* b1          = (const float*)d_in[17];

    setup_kernel<<<513, 256, 0, stream>>>(
        W0, imu_gamma, imu_beta, imu_mean, imu_var,
        frame_gamma, frame_beta, frame_mean, frame_var,
        b0, fc_gamma, fc_beta, fc_mean, fc_var, d_ws);

    fusion_main<<<NBLOCKS, TPB, 0, stream>>>(
        frame_feat, imu_feat, W1, b1, d_ws, (float*)d_out);
}

// Round 11
// 72.776 us; speedup vs baseline: 1.0547x; 1.0126x over previous
//
#include <hip/hip_runtime.h>
#include <hip/hip_bf16.h>

typedef __bf16 bf16x8 __attribute__((ext_vector_type(8)));
typedef float  f32x4  __attribute__((ext_vector_type(4)));
typedef float  f32x16 __attribute__((ext_vector_type(16)));

#define BN_EPS 1e-5f
#define NROWS 131072
#define TPB 256               // 4 waves; wave owns 32 rows x all 256 cols
#define BM 128                // rows per block
#define NBLOCKS (NROWS / BM)  // 1024

#define WAITVM(N) asm volatile("s_waitcnt vmcnt(" #N ")" ::: "memory")

__device__ __forceinline__ void gll16(const void* g, void* l) {
    __builtin_amdgcn_global_load_lds(
        (const __attribute__((address_space(1))) void*)g,
        (__attribute__((address_space(3))) void*)l, 16, 0, 0);
}

// ws layout (bytes):
//   [0, 262144)        W0 packed bf16 for 32x32x16 B-frags:
//                      flat = ((s*8 + t)*64 + lane)*8 + j
//                      n = t*32 + (lane&31); k = s*16 + (lane>>5)*8 + j ; s in [0,32)
//   [262144, 264192)   a_fused f32[512]
//   [264192, 266240)   c_fused f32[512]
//   [266240, 267264)   A_fc f32[256]
//   [267264, 268288)   C_fc f32[256] (b0 folded in)

__global__ __launch_bounds__(256) void setup_kernel(
    const float* __restrict__ W0,
    const float* __restrict__ imu_gamma, const float* __restrict__ imu_beta,
    const float* __restrict__ imu_mean,  const float* __restrict__ imu_var,
    const float* __restrict__ frame_gamma, const float* __restrict__ frame_beta,
    const float* __restrict__ frame_mean,  const float* __restrict__ frame_var,
    const float* __restrict__ b0,
    const float* __restrict__ fc_gamma, const float* __restrict__ fc_beta,
    const float* __restrict__ fc_mean,  const float* __restrict__ fc_var,
    void* __restrict__ ws)
{
    __bf16* w0p    = (__bf16*)ws;
    float* a_fused = (float*)((char*)ws + 262144);
    float* c_fused = a_fused + 512;
    float* A_fc    = c_fused + 512;
    float* C_fc    = A_fc + 256;

    const int b = blockIdx.x;
    if (b < 512) {
        const int flat = b * 256 + threadIdx.x;
        const int j    = flat & 7;
        const int lane = (flat >> 3) & 63;
        const int t    = (flat >> 9) & 7;
        const int s    = flat >> 12;                  // 0..31
        const int n    = t * 32 + (lane & 31);
        const int k    = s * 16 + ((lane >> 5) << 3) + j;
        w0p[flat] = (__bf16)W0[n * 512 + k];
    } else {
        const int t = threadIdx.x;
        const float af = frame_gamma[t] / sqrtf(frame_var[t] + BN_EPS);
        a_fused[t]       = af;
        c_fused[t]       = frame_beta[t] - frame_mean[t] * af;
        const float ai = imu_gamma[t] / sqrtf(imu_var[t] + BN_EPS);
        a_fused[256 + t] = ai;
        c_fused[256 + t] = imu_beta[t] - imu_mean[t] * ai;
        const float A = fc_gamma[t] / sqrtf(fc_var[t] + BN_EPS);
        A_fc[t] = A;
        C_fc[t] = fc_beta[t] - fc_mean[t] * A + A * b0[t];
    }
}

__global__ __launch_bounds__(TPB, 1) void fusion_main(
    const float* __restrict__ frame, const float* __restrict__ imu,
    const float* __restrict__ W1,    const float* __restrict__ b1,
    const void* __restrict__ ws_c,   float* __restrict__ out)
{
    const __bf16* w0p  = (const __bf16*)ws_c;
    const float*  a_g  = (const float*)((const char*)ws_c + 262144);
    const float*  c_g  = a_g + 512;
    const float*  A_fc = c_g + 512;
    const float*  C_fc = A_fc + 256;

    // 52 KB total -> 3 blocks/CU (three independent barrier domains)
    __shared__ __align__(16) __bf16 wpan[3][4096];   // 3 x 8 KB single-k-step W0 panels
    __shared__ __align__(16) float  ring[4][3][512]; // per-wave 3-slot feature ring (2 KB slots)
    __shared__ float asx[512], csx[512];

    const int tid  = threadIdx.x;
    const int wave = tid >> 6;
    const int lane = tid & 63;
    const int row  = lane & 31;   // A-frag row / C col index
    const int hi   = lane >> 5;
    const size_t rowW = (size_t)blockIdx.x * BM + wave * 32;

    // chunk c = one k-step (k=16): 32 rows x 16 f32 = 2 KB = 2 gll.
    // physical granule p at slot-row r holds logical granule p ^ ((r>>1)&3).
    const int fr = lane >> 2;                         // 0..15
    const int fg = (lane & 3) ^ ((lane >> 3) & 3);    // logical granule this lane fetches

    auto issueF = [&](int c) {
        const int cc = (c < 31) ? c : 31;             // tail: re-load last chunk
        const int slot = c % 3;                       // tail slots are provably dead
        const float* srcp = (cc < 16) ? frame : imu;
        const int kb = (cc & 15) * 16;
        float* dstb = &ring[wave][slot][0];
        gll16(srcp + (rowW + fr) * 256 + kb + fg * 4, dstb);
        gll16(srcp + (rowW + 16 + fr) * 256 + kb + fg * 4, dstb + 256);
    };
    auto issueW = [&](int e) {
        const int ee = (e < 31) ? e : 31;             // tail: re-load last panel
        const char* src = (const char*)w0p + ee * 8192 + wave * 1024 + lane * 16;
        char* dst = (char*)&wpan[e % 3][0] + wave * 1024;   // tail panels are dead
        gll16(src, dst);
        gll16(src + 4096, dst + 4096);
    };

    // ---- prologue ----
    asx[tid] = a_g[tid];
    asx[tid + 256] = a_g[tid + 256];
    csx[tid] = c_g[tid];
    csx[tid + 256] = c_g[tid + 256];
    asm volatile("s_waitcnt vmcnt(0)" ::: "memory");   // clean vm queue for counted waits
    issueW(0);
    issueF(0);
    issueW(1);
    issueF(1);
    WAITVM(4);                    // retire W(0),F(0); queue = [W1,F1]
    asm volatile("s_waitcnt lgkmcnt(0)" ::: "memory");
    __builtin_amdgcn_s_barrier();

    f32x16 acc[8];
    #pragma unroll
    for (int t = 0; t < 8; ++t)
        #pragma unroll
        for (int r = 0; r < 16; ++r) acc[t][r] = 0.f;

    auto stepc = [&](int s) {
        const float* sb = &ring[wave][s % 3][0];
        const int sw = (row >> 1) & 3;
        const int g0 = hi * 2;
        const f32x4 x0 = *(const f32x4*)(sb + row * 16 + (((g0 + 0) ^ sw) << 2));
        const f32x4 x1 = *(const f32x4*)(sb + row * 16 + (((g0 + 1) ^ sw) << 2));
        const int kf = s * 16 + hi * 8;
        const f32x4 a0 = *(const f32x4*)(asx + kf);
        const f32x4 a1 = *(const f32x4*)(asx + kf + 4);
        const f32x4 c0 = *(const f32x4*)(csx + kf);
        const f32x4 c1 = *(const f32x4*)(csx + kf + 4);
        bf16x8 af;
        af[0] = (__bf16)fmaxf(fmaf(a0[0], x0[0], c0[0]), 0.f);
        af[1] = (__bf16)fmaxf(fmaf(a0[1], x0[1], c0[1]), 0.f);
        af[2] = (__bf16)fmaxf(fmaf(a0[2], x0[2], c0[2]), 0.f);
        af[3] = (__bf16)fmaxf(fmaf(a0[3], x0[3], c0[3]), 0.f);
        af[4] = (__bf16)fmaxf(fmaf(a1[0], x1[0], c1[0]), 0.f);
        af[5] = (__bf16)fmaxf(fmaf(a1[1], x1[1], c1[1]), 0.f);
        af[6] = (__bf16)fmaxf(fmaf(a1[2], x1[2], c1[2]), 0.f);
        af[7] = (__bf16)fmaxf(fmaf(a1[3], x1[3], c1[3]), 0.f);
        const __bf16* pan = &wpan[s % 3][0];
        #pragma unroll
        for (int t = 0; t < 8; ++t) {
            const bf16x8 bfr = *(const bf16x8*)(pan + (t * 64 + lane) * 8);
            acc[t] = __builtin_amdgcn_mfma_f32_32x32x16_bf16(af, bfr, acc[t], 0, 0, 0);
        }
    };

    // steady phase s: entry queue [W(s+1), F(s+1)]  (both issued in phase s-1)
    //   +W(s+2) +F(s+2) -> stepc(s) -> WAITVM(4) retires W(s+1), F(s+1) -> barrier
    #pragma unroll
    for (int s = 0; s < 32; ++s) {
        issueW(s + 2);
        issueF(s + 2);
        stepc(s);
        WAITVM(4);
        __builtin_amdgcn_s_barrier();
    }
    WAITVM(0);   // drain dangling tail glls before wave exit

    // ---- epilogue: fc BN+ReLU + fc1 + ReLU + clamp ----
    // C/D (32x32): col = t*32 + (lane&31), row-in-tile = (r&3) + 8*(r>>2) + 4*hi
    const float b1_0 = b1[0], b1_1 = b1[1];
    float p0[16], p1[16];
    #pragma unroll
    for (int r = 0; r < 16; ++r) { p0[r] = 0.f; p1[r] = 0.f; }

    #pragma unroll
    for (int t = 0; t < 8; ++t) {
        const int n = t * 32 + row;
        const float A = A_fc[n], C = C_fc[n];
        const float w0n = W1[n], w1n = W1[256 + n];
        #pragma unroll
        for (int r = 0; r < 16; ++r) {
            const float h = fmaxf(fmaf(A, acc[t][r], C), 0.f);
            p0[r] = fmaf(h, w0n, p0[r]);
            p1[r] = fmaf(h, w1n, p1[r]);
        }
    }
    #pragma unroll
    for (int off = 1; off < 32; off <<= 1) {
        #pragma unroll
        for (int r = 0; r < 16; ++r) {
            p0[r] += __shfl_xor(p0[r], off, 64);
            p1[r] += __shfl_xor(p1[r], off, 64);
        }
    }
    if (row == 0) {   // lanes 0 and 32 each write 16 rows
        #pragma unroll
        for (int r = 0; r < 16; ++r) {
            const int rbase = (r & 3) + 8 * (r >> 2) + 4 * hi;
            const float v0 = fminf(fmaxf(p0[r] + b1_0, 0.f), 512.f);
            const float v1 = fminf(fmaxf(p1[r] + b1_1, 0.f), 384.f);
            *(float2*)(out + (rowW + rbase) * 2) = make_float2(v0, v1);
        }
    }
}

extern "C" void kernel_launch(void* const* d_in, const int* in_sizes, int n_in,
                              void* d_out, int out_size, void* d_ws, size_t ws_size,
                              hipStream_t stream) {
    const float* frame_feat  = (const float*)d_in[0];
    const float* imu_feat    = (const float*)d_in[1];
    const float* imu_gamma   = (const float*)d_in[2];
    const float* imu_beta    = (const float*)d_in[3];
    const float* imu_mean    = (const float*)d_in[4];
    const float* imu_var     = (const float*)d_in[5];
    const float* frame_gamma = (const float*)d_in[6];
    const float* frame_beta  = (const float*)d_in[7];
    const float* frame_mean  = (const float*)d_in[8];
    const float* frame_var   = (const float*)d_in[9];
    const float* W0          = (const float*)d_in[10];
    const float* b0          = (const float*)d_in[11];
    const float* fc_gamma    = (const float*)d_in[12];
    const float* fc_beta     = (const float*)d_in[13];
    const float* fc_mean     = (const float*)d_in[14];
    const float* fc_var      = (const float*)d_in[15];
    const float* W1          = (const float*)d_in[16];
    const float* b1          = (const float*)d_in[17];

    setup_kernel<<<513, 256, 0, stream>>>(
        W0, imu_gamma, imu_beta, imu_mean, imu_var,
        frame_gamma, frame_beta, frame_mean, frame_var,
        b0, fc_gamma, fc_beta, fc_mean, fc_var, d_ws);

    fusion_main<<<NBLOCKS, TPB, 0, stream>>>(
        frame_feat, imu_feat, W1, b1, d_ws, (float*)d_out);
}